// Round 7
// baseline (733.873 us; speedup 1.0000x reference)
//
#include <hip/hip_runtime.h>
#include <hip/hip_bf16.h>
#include <math.h>

#define NPTS 524288
#define H 128
#define NB 55
#define NL 59
#define BLK 256
#define PTS_PER_BLK 64
// LDS row: full two-plane layout [hi 256B][lo 256B][pad 16B] = 528B (R0-proven).
// Block owns 64 points -> 64*528 = 33,792 B -> 4 blocks/CU -> 16 waves/CU -> 4 waves/SIMD.
// R6 post-mortem: VGPR_Count=64 both rounds -> backend scheduled for EIGHT waves/SIMD
// (launch_bounds only sets MIN waves -> 128-reg cap, but scheduler minimized to 64 for an
// occupancy LDS can't deliver), leaving zero memory-level parallelism: every weight load
// serialized at L2 latency. amdgpu_waves_per_eu(4,4) pins min=max=4 so the scheduler
// KNOWS the budget is 128 regs and uses the slack to keep the batched A-loads in flight.
#define ROWB 528

typedef __attribute__((ext_vector_type(8))) short short8;
typedef __attribute__((ext_vector_type(4))) float float4v;
typedef __attribute__((ext_vector_type(2))) unsigned uint2v;

// ws layout (bytes)
#define WS_TFHI  0        // [16 elem][64 bone] bf16 hi = 2048
#define WS_B3P   2048     // [64] f32 (59 real, rest 0)
#define WS_W1HI  4096     // [128 feat][128 k] bf16 (UNSCALED: ln2*log2e = 1)
#define WS_W1LO  36864
#define WS_W2HI  69632
#define WS_W2LO  102400
#define WS_W3HI  135168   // [64 feat][128 k] bf16, W3*ln2 (rows>=59 zero)
#define WS_W3LO  151552
#define WS_TFLO  167936   // [16 elem][64 bone] bf16 lo = 2048
#define WS_W0P   169984   // [128 feat][32 k] bf16, 9-slot hi/lo packing of W0*log2e = 8192

#define LOG2E 1.44269504f
#define LN2   0.69314718f

__device__ __forceinline__ float fast_rcp(float x) { return __builtin_amdgcn_rcpf(x); }
__device__ __forceinline__ float fast_rsq(float x) { return __builtin_amdgcn_rsqf(x); }
// log2-domain softplus: returns log2(1 + 2^x); true softplus = ln2 * this (folded into weights)
__device__ __forceinline__ float sp_log2(float x) {
    return __builtin_amdgcn_logf(1.0f + __builtin_amdgcn_exp2f(x));
}
__device__ __forceinline__ float sigf(float x) {
    return fast_rcp(1.0f + __builtin_amdgcn_exp2f(-x * LOG2E));
}
__device__ __forceinline__ unsigned f2u(float f) { union { float f; unsigned u; } v; v.f = f; return v.u; }
__device__ __forceinline__ float u2f(unsigned u) { union { unsigned u; float f; } v; v.u = u; return v.f; }
__device__ __forceinline__ void split_bf(float v, short& hi, short& lo) {
    unsigned uh = (f2u(v) + 0x8000u) & 0xFFFF0000u;
    hi = (short)(uh >> 16);
    float r = v - u2f(uh);
    lo = (short)((f2u(r) + 0x8000u) >> 16);
}
// pack hi-bf16 of (a,b) into one dword [hi(a) | hi(b)<<16], lo-residual dword likewise.
// NOTE: locals only — clang can't bind refs to ext_vector elements (R4/R7 lesson).
__device__ __forceinline__ void pack2_hl(float a, float b, unsigned& hw, unsigned& lw) {
    unsigned ua = f2u(a) + 0x8000u, ub = f2u(b) + 0x8000u;
    hw = __builtin_amdgcn_perm(ub, ua, 0x07060302u);
    float ra = a - u2f(ua & 0xFFFF0000u);
    float rb = b - u2f(ub & 0xFFFF0000u);
    lw = __builtin_amdgcn_perm(f2u(rb) + 0x8000u, f2u(ra) + 0x8000u, 0x07060302u);
}
__device__ __forceinline__ float4v mfma16(short8 a, short8 b, float4v c) {
    return __builtin_amdgcn_mfma_f32_16x16x32_bf16(a, b, c, 0, 0, 0);
}
#define CBAR() asm volatile("" ::: "memory")

// ---- prep: transpose + bf16 hi/lo split of weights into ws (with log2-domain scaling) ----
__global__ void prep_kernel(const float* __restrict__ W0, const float* __restrict__ W1,
                            const float* __restrict__ W2, const float* __restrict__ W3,
                            const float* __restrict__ b3, const float* __restrict__ tfs,
                            char* __restrict__ ws)
{
    const int tid = blockIdx.x * blockDim.x + threadIdx.x;  // 0..16383
    {
        const int n = tid >> 7, k = tid & 127;
        short hi, lo;
        split_bf(W1[k * H + n], hi, lo);
        ((short*)(ws + WS_W1HI))[n * H + k] = hi;
        ((short*)(ws + WS_W1LO))[n * H + k] = lo;
        split_bf(W2[k * H + n], hi, lo);
        ((short*)(ws + WS_W2HI))[n * H + k] = hi;
        ((short*)(ws + WS_W2LO))[n * H + k] = lo;
    }
    if (tid < 64 * 128) {
        const int n = tid >> 7, k = tid & 127;
        float w = (n < NL) ? W3[k * NL + n] * LN2 : 0.0f;   // acts stored in log2 domain
        short hi, lo;
        split_bf(w, hi, lo);
        ((short*)(ws + WS_W3HI))[n * H + k] = hi;
        ((short*)(ws + WS_W3LO))[n * H + k] = lo;
    }
    if (tid < 16 * 64) {
        const int e = tid >> 6, b = tid & 63;
        float w = (b < NB) ? tfs[b * 16 + e] : 0.0f;
        short hi, lo;
        split_bf(w, hi, lo);
        ((short*)(ws + WS_TFHI))[e * 64 + b] = hi;
        ((short*)(ws + WS_TFLO))[e * 64 + b] = lo;
    }
    if (tid < 128 * 32) {
        // W0P 9-slot packing: slots 0-2 = Whi(x,y,z), 3-5 = Whi, 6-8 = Wlo; W0 scaled by log2e
        const int n = tid >> 5, k = tid & 31;
        short s = 0;
        if (k < 9) {
            const int kk = (k < 3) ? k : ((k < 6) ? k - 3 : k - 6);
            short hi, lo;
            split_bf(W0[kk * H + n] * LOG2E, hi, lo);
            s = (k < 6) ? hi : lo;
        }
        ((short*)(ws + WS_W0P))[n * 32 + k] = s;
    }
    if (tid < 64) {
        ((float*)(ws + WS_B3P))[tid] = (tid < NL) ? b3[tid] : 0.0f;
    }
}

// 128-in MFMA layer, full two-plane row (hi [0,256), lo [256,512)), ONE 16-row tile per wave.
// A-loads BATCHED: per k0, all NFT hi-weights load into an unrolled register array (one
// vmcnt group), then 2 MFMAs each; then the NFT lo-weights reuse the same regs, 1 MFMA each.
// Live peak: acc 32 + Ahi 32 + Alo(in flight) 32 + B 16 = 112 regs — inside the 128 budget
// that amdgpu_waves_per_eu(4,4) makes the scheduler actually target.
// Same 3 compensation terms per (ft,k0) in the same acc order — numerics identical.
// Writeback overwrites both planes after all reads issued — same-wave, program-ordered DS
// ops (R0-validated in-place pattern); CBAR pins source order.
template<int NFT, bool SOFTPLUS>
__device__ __forceinline__ void mfma_layer(char* rowp, int l15, int g,
                                           const short* __restrict__ Whi,
                                           const short* __restrict__ Wlo,
                                           const float* __restrict__ bias, float bscale)
{
    float4v acc[NFT];
#pragma unroll
    for (int ft = 0; ft < NFT; ++ft) {
        float4v bv = *(const float4v*)(bias + ft * 16 + g * 4);
        acc[ft] = bv * bscale;
    }
#pragma unroll
    for (int k0 = 0; k0 < 128; k0 += 32) {
        short8 Bhi = *(const short8*)(rowp + 2 * k0 + 16 * g);
        short8 Blo = *(const short8*)(rowp + 256 + 2 * k0 + 16 * g);
        short8 A[NFT];
        // batch all hi-weight loads (NFT in flight, one wait)
#pragma unroll
        for (int ft = 0; ft < NFT; ++ft)
            A[ft] = *(const short8*)(Whi + (ft * 16 + l15) * H + k0 + g * 8);
#pragma unroll
        for (int ft = 0; ft < NFT; ++ft) {
            acc[ft] = mfma16(A[ft], Bhi, acc[ft]);
            acc[ft] = mfma16(A[ft], Blo, acc[ft]);
        }
        // batch all lo-weight loads (reuses the A regs)
#pragma unroll
        for (int ft = 0; ft < NFT; ++ft)
            A[ft] = *(const short8*)(Wlo + (ft * 16 + l15) * H + k0 + g * 8);
#pragma unroll
        for (int ft = 0; ft < NFT; ++ft)
            acc[ft] = mfma16(A[ft], Bhi, acc[ft]);
    }
    CBAR();
#pragma unroll
    for (int ft = 0; ft < NFT; ++ft) {
        if constexpr (SOFTPLUS) {
            float s0 = sp_log2(acc[ft].x);
            float s1 = sp_log2(acc[ft].y);
            float s2 = sp_log2(acc[ft].z);
            float s3 = sp_log2(acc[ft].w);
            unsigned hx, lx, hy, ly;
            pack2_hl(s0, s1, hx, lx);
            pack2_hl(s2, s3, hy, ly);
            uint2v hw, lw;
            hw.x = hx; hw.y = hy;
            lw.x = lx; lw.y = ly;
            *(uint2v*)(rowp + (ft * 16 + g * 4) * 2) = hw;
            *(uint2v*)(rowp + 256 + (ft * 16 + g * 4) * 2) = lw;
        } else {
            *(float4v*)(rowp + (ft * 16 + g * 4) * 4) = acc[ft];
        }
    }
    CBAR();
}

// ======================= kernel 1: MLP + hierarchical softmax + T_fwd =======================
// 4 waves/block, each wave self-contained on its 16 rows (no barriers). Tail (softmax, T pack)
// runs on lanes 0-15 of each wave; tf store uses all 64 lanes. Pose math lives in kernel 2.
// amdgpu_waves_per_eu(4,4): pin scheduler's occupancy model to the LDS-imposed reality so it
// uses the full 128-reg budget for load batching (R6: it targeted 8 waves -> 64 regs -> no MLP).
__global__ void __attribute__((amdgpu_flat_work_group_size(BLK, BLK)))
__attribute__((amdgpu_waves_per_eu(4, 4)))
skin_mlp(const float* __restrict__ xyz,
         const float* __restrict__ amn, const float* __restrict__ amx,
         const float* __restrict__ b0, const float* __restrict__ b1,
         const float* __restrict__ b2, const char* __restrict__ ws,
         float* __restrict__ out)
{
    __shared__ __align__(16) char lds[PTS_PER_BLK * ROWB];  // 33,792 B
    const int tid = threadIdx.x;
    const int lane = tid & 63;
    const int wv = tid >> 6;
    const int l15 = lane & 15;
    const int g = lane >> 4;
    const int mrow0 = wv * 16;
    const int nbase = blockIdx.x * PTS_PER_BLK + mrow0;

    // the one row this lane reads B-fragments from / writes its output quarter to
    char* rowp = lds + (mrow0 + l15) * ROWB;

    // ---- staging (lanes 0-15: one point per lane): xyz normalize, 9-slot hi/lo L0 input ----
    if (lane < 16) {
        const int n = nbase + lane;   // l15 == lane
        const float x = xyz[3 * n + 0];
        const float y = xyz[3 * n + 1];
        const float z = xyz[3 * n + 2];
        const float xn = 2.0f * (x - amn[0]) * fast_rcp(amx[0] - amn[0]) - 1.0f;
        const float yn = 2.0f * (y - amn[1]) * fast_rcp(amx[1] - amn[1]) - 1.0f;
        const float zn = 2.0f * (z - amn[2]) * fast_rcp(amx[2] - amn[2]) - 1.0f;
        short xh, xl, yh, yl, zh, zl;
        split_bf(xn, xh, xl);
        split_bf(yn, yh, yl);
        split_bf(zn, zh, zl);
        short8 s0v; short8 zer = {0, 0, 0, 0, 0, 0, 0, 0};
        s0v[0] = xh; s0v[1] = yh; s0v[2] = zh; s0v[3] = xl;
        s0v[4] = yl; s0v[5] = zl; s0v[6] = xh; s0v[7] = yh;
        short8 s1v = zer; s1v[0] = zh;
        *(short8*)(rowp) = s0v;
        *(short8*)(rowp + 16) = s1v;
        *(short8*)(rowp + 32) = zer;
        *(short8*)(rowp + 48) = zer;
    }
    CBAR();

    // ---- layer 0 via MFMA: K=32, batched A; A = 9-slot packed W0*log2e ----
    {
        const short* W0p = (const short*)(ws + WS_W0P);
        float4v acc[8];
#pragma unroll
        for (int ft = 0; ft < 8; ++ft) {
            float4v bv = *(const float4v*)(b0 + ft * 16 + g * 4);
            acc[ft] = bv * LOG2E;
        }
        short8 B = *(const short8*)(rowp + 16 * g);
        short8 A[8];
#pragma unroll
        for (int ft = 0; ft < 8; ++ft)
            A[ft] = *(const short8*)(W0p + (ft * 16 + l15) * 32 + g * 8);
#pragma unroll
        for (int ft = 0; ft < 8; ++ft)
            acc[ft] = mfma16(A[ft], B, acc[ft]);
        CBAR();
        // writeback: hi plane [0,256) (overwrites staged input — reads issued), lo [256,512)
#pragma unroll
        for (int ft = 0; ft < 8; ++ft) {
            float s0 = sp_log2(acc[ft].x);
            float s1 = sp_log2(acc[ft].y);
            float s2 = sp_log2(acc[ft].z);
            float s3 = sp_log2(acc[ft].w);
            unsigned hx, lx, hy, ly;
            pack2_hl(s0, s1, hx, lx);
            pack2_hl(s2, s3, hy, ly);
            uint2v hw, lw;
            hw.x = hx; hw.y = hy;
            lw.x = lx; lw.y = ly;
            *(uint2v*)(rowp + (ft * 16 + g * 4) * 2) = hw;
            *(uint2v*)(rowp + 256 + (ft * 16 + g * 4) * 2) = lw;
        }
        CBAR();
    }

    // ---- layers 1,2: 128 -> 128 softplus(log2); layer 3: 128 -> 64(59) logits fp32 ----
    mfma_layer<8, true>(rowp, l15, g, (const short*)(ws + WS_W1HI),
                        (const short*)(ws + WS_W1LO), b1, LOG2E);
    mfma_layer<8, true>(rowp, l15, g, (const short*)(ws + WS_W2HI),
                        (const short*)(ws + WS_W2LO), b2, LOG2E);
    mfma_layer<4, false>(rowp, l15, g, (const short*)(ws + WS_W3HI),
                         (const short*)(ws + WS_W3LO), (const float*)(ws + WS_B3P), 1.0f);

    // ---- tail part 1 (lanes 0-15): hierarchical softmax over own row's logits, pack p ----
    if (lane < 16) {
        const float* lrow = (const float*)rowp;   // fp32 logits [0,256)
#define LG(i) lrow[(i)]
        float p[NB];
#define BR(par, ch)                                         \
    do {                                                    \
        float a_ = p[par];                                  \
        float s_ = sigf(LG(ch));                            \
        p[ch] = a_ * s_;                                    \
        p[par] = a_ * (1.0f - s_);                          \
    } while (0)
#define SUB3(par, gt, c0, c1, c2)                                            \
    do {                                                                     \
        float a_ = p[par];                                                   \
        float g_ = sigf(LG(gt));                                             \
        float l0_ = LG(c0), l1_ = LG(c1), l2_ = LG(c2);                      \
        float m_ = fmaxf(l0_, fmaxf(l1_, l2_));                              \
        float e0_ = __expf(l0_ - m_);                                        \
        float e1_ = __expf(l1_ - m_);                                        \
        float e2_ = __expf(l2_ - m_);                                        \
        float inv_ = a_ * g_ * fast_rcp(e0_ + e1_ + e2_);                    \
        p[c0] = e0_ * inv_;                                                  \
        p[c1] = e1_ * inv_;                                                  \
        p[c2] = e2_ * inv_;                                                  \
        p[par] = a_ * (1.0f - g_);                                           \
    } while (0)
#define SUB5(par, gt, c0, c1, c2, c3, c4)                                    \
    do {                                                                     \
        float a_ = p[par];                                                   \
        float g_ = sigf(LG(gt));                                             \
        float l0_ = LG(c0), l1_ = LG(c1), l2_ = LG(c2), l3_ = LG(c3), l4_ = LG(c4); \
        float m_ = fmaxf(fmaxf(fmaxf(l0_, l1_), fmaxf(l2_, l3_)), l4_);      \
        float e0_ = __expf(l0_ - m_);                                        \
        float e1_ = __expf(l1_ - m_);                                        \
        float e2_ = __expf(l2_ - m_);                                        \
        float e3_ = __expf(l3_ - m_);                                        \
        float e4_ = __expf(l4_ - m_);                                        \
        float inv_ = a_ * g_ * fast_rcp(e0_ + e1_ + e2_ + e3_ + e4_);        \
        p[c0] = e0_ * inv_;                                                  \
        p[c1] = e1_ * inv_;                                                  \
        p[c2] = e2_ * inv_;                                                  \
        p[c3] = e3_ * inv_;                                                  \
        p[c4] = e4_ * inv_;                                                  \
        p[par] = a_ * (1.0f - g_);                                           \
    } while (0)

        {
            float s0_ = sigf(LG(0));
            float l1_ = LG(1), l2_ = LG(2), l3_ = LG(3);
            float m_ = fmaxf(l1_, fmaxf(l2_, l3_));
            float e1_ = __expf(l1_ - m_);
            float e2_ = __expf(l2_ - m_);
            float e3_ = __expf(l3_ - m_);
            float inv_ = s0_ * fast_rcp(e1_ + e2_ + e3_);
            p[1] = e1_ * inv_;
            p[2] = e2_ * inv_;
            p[3] = e3_ * inv_;
            p[0] = 1.0f - s0_;
        }
        BR(1, 4); BR(2, 5); BR(3, 6);
        BR(4, 7); BR(5, 8); BR(6, 9);
        BR(7, 10); BR(8, 11);
        SUB3(9, 55, 12, 13, 14);
        BR(12, 15);
        BR(13, 16); BR(14, 17);
        BR(16, 18); BR(17, 19);
        BR(18, 20); BR(19, 21);
        SUB3(15, 56, 22, 23, 24);
        SUB5(20, 57, 25, 28, 31, 34, 37);
        SUB5(21, 58, 40, 43, 46, 49, 52);
        BR(25, 26); BR(28, 29); BR(31, 32); BR(34, 35); BR(37, 38);
        BR(26, 27); BR(29, 30); BR(32, 33); BR(35, 36); BR(38, 39);
        BR(40, 41); BR(43, 44); BR(46, 47); BR(49, 50); BR(52, 53);
        BR(41, 42); BR(44, 45); BR(47, 48); BR(50, 51); BR(53, 54);

        // pack p into own row: hi plane [0,128), lo plane [128,256) (logit reads above done)
#pragma unroll
        for (int jj = 0; jj < 64; jj += 4) {
            float v0 = (jj + 0 < NB) ? p[jj + 0] : 0.0f;
            float v1 = (jj + 1 < NB) ? p[jj + 1] : 0.0f;
            float v2 = (jj + 2 < NB) ? p[jj + 2] : 0.0f;
            float v3 = (jj + 3 < NB) ? p[jj + 3] : 0.0f;
            unsigned hx, lx, hy, ly;
            pack2_hl(v0, v1, hx, lx);
            pack2_hl(v2, v3, hy, ly);
            uint2v hw, lw;
            hw.x = hx; hw.y = hy;
            lw.x = lx; lw.y = ly;
            *(uint2v*)(rowp + 2 * jj) = hw;
            *(uint2v*)(rowp + 128 + 2 * jj) = lw;
        }
    }
    CBAR();

    // ---- T_fwd = p @ tfs via MFMA (all lanes): p hi [0,128), lo [128,256); A = tfs^T hi/lo.
    //      All 4 A-loads batched upfront (one vmcnt group). ----
    {
        const short* Ahi_p = (const short*)(ws + WS_TFHI);
        const short* Alo_p = (const short*)(ws + WS_TFLO);
        short8 Ah0 = *(const short8*)(Ahi_p + l15 * 64 + 0 + g * 8);
        short8 Al0 = *(const short8*)(Alo_p + l15 * 64 + 0 + g * 8);
        short8 Ah1 = *(const short8*)(Ahi_p + l15 * 64 + 32 + g * 8);
        short8 Al1 = *(const short8*)(Alo_p + l15 * 64 + 32 + g * 8);
        float4v acc = (float4v){0.f, 0.f, 0.f, 0.f};
        {
            short8 Bhi = *(const short8*)(rowp + 0 + 16 * g);
            short8 Blo = *(const short8*)(rowp + 128 + 0 + 16 * g);
            acc = mfma16(Ah0, Bhi, acc);
            acc = mfma16(Ah0, Blo, acc);
            acc = mfma16(Al0, Bhi, acc);
        }
        {
            short8 Bhi = *(const short8*)(rowp + 64 + 16 * g);
            short8 Blo = *(const short8*)(rowp + 128 + 64 + 16 * g);
            acc = mfma16(Ah1, Bhi, acc);
            acc = mfma16(Ah1, Blo, acc);
            acc = mfma16(Al1, Bhi, acc);
        }
        CBAR();
        // write T to [256,320) — disjoint from p reads [0,256), no hazard
        *(float4v*)(rowp + 256 + g * 16) = acc;
    }
    CBAR();

    // ---- tail part 2 (ALL 64 lanes): stream T rows coalesced to tf output ----
    {
        // lane -> (point = lane>>2, row j = lane&3); any lane may read any LDS row.
        const int pt = lane >> 2;
        const int j = lane & 3;
        const int n = blockIdx.x * PTS_PER_BLK + mrow0 + pt;
        float4v t = *(const float4v*)(lds + (mrow0 + pt) * ROWB + 256 + 16 * j);
        float4* tf = (float4*)(out + 16 * (size_t)NPTS);
        tf[4 * n + j] = make_float4(t.x, t.y, t.z, t.w);
    }
}

// ======================= kernel 2: pose tail (elementwise, memory-bound) =======================
// Reads T_fwd back from out's tf section (stream-ordered after skin_mlp), plus xyz/quats;
// writes x_bar, rot_bar, quat_bar. ~40 VGPRs, no LDS -> full occupancy, HBM-bound ~82 MB.
__global__ void __launch_bounds__(256)
pose_kernel(const float* __restrict__ xyz, const float* __restrict__ quats,
            float* __restrict__ out)
{
    const int n = blockIdx.x * 256 + threadIdx.x;
    const float4* tf = (const float4*)(out + 16 * (size_t)NPTS);
    const float4 t0v = tf[4 * n + 0];
    const float4 t1v = tf[4 * n + 1];
    const float4 t2v = tf[4 * n + 2];

    const float x = xyz[3 * n + 0];
    const float y = xyz[3 * n + 1];
    const float z = xyz[3 * n + 2];

    const float xb0 = fmaf(t0v.x, x, fmaf(t0v.y, y, fmaf(t0v.z, z, t0v.w)));
    const float xb1 = fmaf(t1v.x, x, fmaf(t1v.y, y, fmaf(t1v.z, z, t1v.w)));
    const float xb2 = fmaf(t2v.x, x, fmaf(t2v.y, y, fmaf(t2v.z, z, t2v.w)));

    const float4 qv = ((const float4*)quats)[n];
    float qr = qv.x, qx = qv.y, qy = qv.z, qz = qv.w;
    {
        float inv = fast_rsq(qr * qr + qx * qx + qy * qy + qz * qz);
        qr *= inv; qx *= inv; qy *= inv; qz *= inv;
    }
    const float R00 = 1.0f - 2.0f * (qy * qy + qz * qz);
    const float R01 = 2.0f * (qx * qy - qr * qz);
    const float R02 = 2.0f * (qx * qz + qr * qy);
    const float R10 = 2.0f * (qx * qy + qr * qz);
    const float R11 = 1.0f - 2.0f * (qx * qx + qz * qz);
    const float R12 = 2.0f * (qy * qz - qr * qx);
    const float R20 = 2.0f * (qx * qz - qr * qy);
    const float R21 = 2.0f * (qy * qz + qr * qx);
    const float R22 = 1.0f - 2.0f * (qx * qx + qy * qy);

    const float B00 = t0v.x * R00 + t0v.y * R10 + t0v.z * R20;
    const float B01 = t0v.x * R01 + t0v.y * R11 + t0v.z * R21;
    const float B02 = t0v.x * R02 + t0v.y * R12 + t0v.z * R22;
    const float B10 = t1v.x * R00 + t1v.y * R10 + t1v.z * R20;
    const float B11 = t1v.x * R01 + t1v.y * R11 + t1v.z * R21;
    const float B12 = t1v.x * R02 + t1v.y * R12 + t1v.z * R22;
    const float B20 = t2v.x * R00 + t2v.y * R10 + t2v.z * R20;
    const float B21 = t2v.x * R01 + t2v.y * R11 + t2v.z * R21;
    const float B22 = t2v.x * R02 + t2v.y * R12 + t2v.z * R22;

    const float t0 = 1.0f + B00 + B11 + B22;
    const float t1 = 1.0f + B00 - B11 - B22;
    const float t2 = 1.0f - B00 + B11 - B22;
    const float t3 = 1.0f - B00 - B11 + B22;
    const float s0 = 0.5f * fast_rsq(fmaxf(t0, 1e-8f));
    const float s1 = 0.5f * fast_rsq(fmaxf(t1, 1e-8f));
    const float s2 = 0.5f * fast_rsq(fmaxf(t2, 1e-8f));
    const float s3 = 0.5f * fast_rsq(fmaxf(t3, 1e-8f));
    const float q0w = t0 * s0, q0x = (B21 - B12) * s0, q0y = (B02 - B20) * s0, q0z = (B10 - B01) * s0;
    const float q1w = (B21 - B12) * s1, q1x = t1 * s1, q1y = (B01 + B10) * s1, q1z = (B02 + B20) * s1;
    const float q2w = (B02 - B20) * s2, q2x = (B01 + B10) * s2, q2y = t2 * s2, q2z = (B12 + B21) * s2;
    const float q3w = (B10 - B01) * s3, q3x = (B02 + B20) * s3, q3y = (B12 + B21) * s3, q3z = t3 * s3;

    int best = 0;
    float tb = t0;
    if (t1 > tb) { best = 1; tb = t1; }
    if (t2 > tb) { best = 2; tb = t2; }
    if (t3 > tb) { best = 3; tb = t3; }

    float Qw = (best == 0) ? q0w : (best == 1) ? q1w : (best == 2) ? q2w : q3w;
    float Qx = (best == 0) ? q0x : (best == 1) ? q1x : (best == 2) ? q2x : q3x;
    float Qy = (best == 0) ? q0y : (best == 1) ? q1y : (best == 2) ? q2y : q3y;
    float Qz = (best == 0) ? q0z : (best == 1) ? q1z : (best == 2) ? q2z : q3z;
    {
        float inv = fast_rsq(Qw * Qw + Qx * Qx + Qy * Qy + Qz * Qz);
        Qw *= inv; Qx *= inv; Qy *= inv; Qz *= inv;
    }

    out[3 * n + 0] = xb0;
    out[3 * n + 1] = xb1;
    out[3 * n + 2] = xb2;
    float* rb = out + 3 * (size_t)NPTS;
    rb[9 * n + 0] = B00; rb[9 * n + 1] = B01; rb[9 * n + 2] = B02;
    rb[9 * n + 3] = B10; rb[9 * n + 4] = B11; rb[9 * n + 5] = B12;
    rb[9 * n + 6] = B20; rb[9 * n + 7] = B21; rb[9 * n + 8] = B22;
    float4* qb = (float4*)(out + 12 * (size_t)NPTS);
    qb[n] = make_float4(Qw, Qx, Qy, Qz);
}

extern "C" void kernel_launch(void* const* d_in, const int* in_sizes, int n_in,
                              void* d_out, int out_size, void* d_ws, size_t ws_size,
                              hipStream_t stream) {
    const float* xyz = (const float*)d_in[0];
    const float* quats = (const float*)d_in[1];
    const float* tfs = (const float*)d_in[2];
    const float* amn = (const float*)d_in[3];
    const float* amx = (const float*)d_in[4];
    const float* W0 = (const float*)d_in[5];
    const float* b0 = (const float*)d_in[6];
    const float* W1 = (const float*)d_in[7];
    const float* b1 = (const float*)d_in[8];
    const float* W2 = (const float*)d_in[9];
    const float* b2 = (const float*)d_in[10];
    const float* W3 = (const float*)d_in[11];
    const float* b3 = (const float*)d_in[12];
    float* out = (float*)d_out;
    char* ws = (char*)d_ws;

    hipLaunchKernelGGL(prep_kernel, dim3(64), dim3(256), 0, stream, W0, W1, W2, W3, b3, tfs, ws);
    hipLaunchKernelGGL(skin_mlp, dim3(NPTS / PTS_PER_BLK), dim3(BLK), 0, stream,
                       xyz, amn, amx, b0, b1, b2, (const char*)ws, out);
    hipLaunchKernelGGL(pose_kernel, dim3(NPTS / 256), dim3(256), 0, stream,
                       xyz, quats, out);
}

// Round 8
// 364.823 us; speedup vs baseline: 2.0116x; 2.0116x over previous
//
#include <hip/hip_runtime.h>
#include <hip/hip_bf16.h>
#include <math.h>

#define NPTS 524288
#define H 128
#define NB 55
#define NL 59
#define BLK 256
#define PTS_PER_BLK 128
// acts row: full two-plane layout [hi 256B][lo 256B][pad 16B] = 528B (R0-proven).
// LDS: acts 128*528=67584 + wbuf 65536 + bbuf 2048 = 135168 B -> 1 block/CU, 1 wave/SIMD.
// R7 post-mortem: per-wave stall ~190K cyc with global in-loop A-loads, insensitive to every
// schedule knob. This version removes ALL global loads from the main loop: weights are staged
// per-layer into LDS (reg-staged, XOR-swizzled writes to kill the 256B-row bank conflicts),
// A/B/bias all read via ds_read_b128 — the regime where the compiler's fine-grained lgkmcnt
// scheduling is proven near-optimal (m97).
#define ROWB 528

typedef __attribute__((ext_vector_type(8))) short short8;
typedef __attribute__((ext_vector_type(4))) float float4v;
typedef __attribute__((ext_vector_type(2))) unsigned uint2v;

// ws layout (bytes)
#define WS_TFHI  0        // [16 elem][64 bone] bf16 hi = 2048
#define WS_B3P   2048     // [64] f32 (59 real, rest 0)
#define WS_W1HI  4096     // [128 feat][128 k] bf16 (UNSCALED: ln2*log2e = 1)
#define WS_W1LO  36864
#define WS_W2HI  69632
#define WS_W2LO  102400
#define WS_W3HI  135168   // [64 feat][128 k] bf16, W3*ln2 (rows>=59 zero)
#define WS_W3LO  151552
#define WS_TFLO  167936   // [16 elem][64 bone] bf16 lo = 2048
#define WS_W0P   169984   // [128 feat][32 k] bf16, 9-slot hi/lo packing of W0*log2e = 8192

// wbuf regions during the L3/T phase
#define WB_W3HI  0
#define WB_W3LO  16384
#define WB_TFHI  32768
#define WB_TFLO  34816

#define LOG2E 1.44269504f
#define LN2   0.69314718f

__device__ __forceinline__ float fast_rcp(float x) { return __builtin_amdgcn_rcpf(x); }
__device__ __forceinline__ float fast_rsq(float x) { return __builtin_amdgcn_rsqf(x); }
// log2-domain softplus: returns log2(1 + 2^x); true softplus = ln2 * this (folded into weights)
__device__ __forceinline__ float sp_log2(float x) {
    return __builtin_amdgcn_logf(1.0f + __builtin_amdgcn_exp2f(x));
}
__device__ __forceinline__ float sigf(float x) {
    return fast_rcp(1.0f + __builtin_amdgcn_exp2f(-x * LOG2E));
}
__device__ __forceinline__ unsigned f2u(float f) { union { float f; unsigned u; } v; v.f = f; return v.u; }
__device__ __forceinline__ float u2f(unsigned u) { union { unsigned u; float f; } v; v.u = u; return v.f; }
__device__ __forceinline__ void split_bf(float v, short& hi, short& lo) {
    unsigned uh = (f2u(v) + 0x8000u) & 0xFFFF0000u;
    hi = (short)(uh >> 16);
    float r = v - u2f(uh);
    lo = (short)((f2u(r) + 0x8000u) >> 16);
}
// pack hi-bf16 of (a,b) into one dword [hi(a) | hi(b)<<16], lo-residual dword likewise.
// NOTE: locals only — clang can't bind refs to ext_vector elements (R4/R7 lesson).
__device__ __forceinline__ void pack2_hl(float a, float b, unsigned& hw, unsigned& lw) {
    unsigned ua = f2u(a) + 0x8000u, ub = f2u(b) + 0x8000u;
    hw = __builtin_amdgcn_perm(ub, ua, 0x07060302u);
    float ra = a - u2f(ua & 0xFFFF0000u);
    float rb = b - u2f(ub & 0xFFFF0000u);
    lw = __builtin_amdgcn_perm(f2u(rb) + 0x8000u, f2u(ra) + 0x8000u, 0x07060302u);
}
__device__ __forceinline__ float4v mfma16(short8 a, short8 b, float4v c) {
    return __builtin_amdgcn_mfma_f32_16x16x32_bf16(a, b, c, 0, 0, 0);
}
#define CBAR() asm volatile("" ::: "memory")

// ---- prep: transpose + bf16 hi/lo split of weights into ws (with log2-domain scaling) ----
__global__ void prep_kernel(const float* __restrict__ W0, const float* __restrict__ W1,
                            const float* __restrict__ W2, const float* __restrict__ W3,
                            const float* __restrict__ b3, const float* __restrict__ tfs,
                            char* __restrict__ ws)
{
    const int tid = blockIdx.x * blockDim.x + threadIdx.x;  // 0..16383
    {
        const int n = tid >> 7, k = tid & 127;
        short hi, lo;
        split_bf(W1[k * H + n], hi, lo);
        ((short*)(ws + WS_W1HI))[n * H + k] = hi;
        ((short*)(ws + WS_W1LO))[n * H + k] = lo;
        split_bf(W2[k * H + n], hi, lo);
        ((short*)(ws + WS_W2HI))[n * H + k] = hi;
        ((short*)(ws + WS_W2LO))[n * H + k] = lo;
    }
    if (tid < 64 * 128) {
        const int n = tid >> 7, k = tid & 127;
        float w = (n < NL) ? W3[k * NL + n] * LN2 : 0.0f;   // acts stored in log2 domain
        short hi, lo;
        split_bf(w, hi, lo);
        ((short*)(ws + WS_W3HI))[n * H + k] = hi;
        ((short*)(ws + WS_W3LO))[n * H + k] = lo;
    }
    if (tid < 16 * 64) {
        const int e = tid >> 6, b = tid & 63;
        float w = (b < NB) ? tfs[b * 16 + e] : 0.0f;
        short hi, lo;
        split_bf(w, hi, lo);
        ((short*)(ws + WS_TFHI))[e * 64 + b] = hi;
        ((short*)(ws + WS_TFLO))[e * 64 + b] = lo;
    }
    if (tid < 128 * 32) {
        // W0P 9-slot packing: slots 0-2 = Whi(x,y,z), 3-5 = Whi, 6-8 = Wlo; W0 scaled by log2e
        const int n = tid >> 5, k = tid & 31;
        short s = 0;
        if (k < 9) {
            const int kk = (k < 3) ? k : ((k < 6) ? k - 3 : k - 6);
            short hi, lo;
            split_bf(W0[kk * H + n] * LOG2E, hi, lo);
            s = (k < 6) ? hi : lo;
        }
        ((short*)(ws + WS_W0P))[n * 32 + k] = s;
    }
    if (tid < 64) {
        ((float*)(ws + WS_B3P))[tid] = (tid < NL) ? b3[tid] : 0.0f;
    }
}

// Cooperative stage of a [nfeat][256B] weight half into LDS with XOR bank-swizzle.
// Write side swizzles (reg-staged, so rule #21 doesn't bite); read uses the same involution:
//   chunk c of row f lives at  f*256 + ((c ^ (f&7)) << 4).
// PER = (bytes/16)/256 chunks per thread.
template<int PER>
__device__ __forceinline__ void stage_swz(const char* __restrict__ src, char* dst, int tid)
{
    short8 v[PER];
#pragma unroll
    for (int i = 0; i < PER; ++i)
        v[i] = *(const short8*)(src + (i * 256 + tid) * 16);
#pragma unroll
    for (int i = 0; i < PER; ++i) {
        const int idx = i * 256 + tid;
        const int f = idx >> 4;
        const int c = idx & 15;
        *(short8*)(dst + f * 256 + ((c ^ (f & 7)) << 4)) = v[i];
    }
}

// 128-in MFMA layer, all operands in LDS. Wave owns 2 row-tiles (32 points).
// Per (ft,t) chain order: Ahi*Bhi, Ahi*Blo, Alo*Bhi — identical to all prior rounds.
// In-place writeback after all reads issued (same-wave program-ordered DS, R0-validated).
template<int NFT, bool SOFTPLUS>
__device__ __forceinline__ void mfma_layer_lds(char* acts, int mrow0, int l15, int g,
                                               const char* __restrict__ whi,
                                               const char* __restrict__ wlo,
                                               const float* __restrict__ bias, float bscale)
{
    float4v acc[NFT][2];
#pragma unroll
    for (int ft = 0; ft < NFT; ++ft) {
        float4v bv = *(const float4v*)(bias + ft * 16 + g * 4);
        bv *= bscale;
        acc[ft][0] = bv;
        acc[ft][1] = bv;
    }
    const int sw = l15 & 7;
#pragma unroll
    for (int k0 = 0; k0 < 128; k0 += 32) {
        short8 Bhi[2], Blo[2];
#pragma unroll
        for (int t = 0; t < 2; ++t) {
            const char* rp = acts + (mrow0 + t * 16 + l15) * ROWB;
            Bhi[t] = *(const short8*)(rp + 2 * k0 + 16 * g);
            Blo[t] = *(const short8*)(rp + 256 + 2 * k0 + 16 * g);
        }
        const int csw = (((k0 >> 3) + g) ^ sw) << 4;
        short8 A[NFT];
#pragma unroll
        for (int ft = 0; ft < NFT; ++ft)
            A[ft] = *(const short8*)(whi + (ft * 16 + l15) * 256 + csw);
#pragma unroll
        for (int ft = 0; ft < NFT; ++ft) {
            acc[ft][0] = mfma16(A[ft], Bhi[0], acc[ft][0]);
            acc[ft][1] = mfma16(A[ft], Bhi[1], acc[ft][1]);
            acc[ft][0] = mfma16(A[ft], Blo[0], acc[ft][0]);
            acc[ft][1] = mfma16(A[ft], Blo[1], acc[ft][1]);
        }
#pragma unroll
        for (int ft = 0; ft < NFT; ++ft)
            A[ft] = *(const short8*)(wlo + (ft * 16 + l15) * 256 + csw);
#pragma unroll
        for (int ft = 0; ft < NFT; ++ft) {
            acc[ft][0] = mfma16(A[ft], Bhi[0], acc[ft][0]);
            acc[ft][1] = mfma16(A[ft], Bhi[1], acc[ft][1]);
        }
    }
    CBAR();
#pragma unroll
    for (int ft = 0; ft < NFT; ++ft) {
#pragma unroll
        for (int t = 0; t < 2; ++t) {
            char* rowp = acts + (mrow0 + t * 16 + l15) * ROWB;
            if constexpr (SOFTPLUS) {
                float s0 = sp_log2(acc[ft][t].x);
                float s1 = sp_log2(acc[ft][t].y);
                float s2 = sp_log2(acc[ft][t].z);
                float s3 = sp_log2(acc[ft][t].w);
                unsigned hx, lx, hy, ly;
                pack2_hl(s0, s1, hx, lx);
                pack2_hl(s2, s3, hy, ly);
                uint2v hw, lw;
                hw.x = hx; hw.y = hy;
                lw.x = lx; lw.y = ly;
                *(uint2v*)(rowp + (ft * 16 + g * 4) * 2) = hw;
                *(uint2v*)(rowp + 256 + (ft * 16 + g * 4) * 2) = lw;
            } else {
                *(float4v*)(rowp + (ft * 16 + g * 4) * 4) = acc[ft][t];
            }
        }
    }
    CBAR();
}

// ======================= kernel 1: MLP + hierarchical softmax + T_fwd =======================
// 1 block/CU (LDS 135KB). Per layer: cooperative stage -> barrier -> LDS-only compute -> barrier.
// Tail: lanes 0-31 each own one of the wave's 32 points. Pose math lives in kernel 2.
__global__ void __launch_bounds__(BLK, 1)
skin_mlp(const float* __restrict__ xyz,
         const float* __restrict__ amn, const float* __restrict__ amx,
         const float* __restrict__ b0, const float* __restrict__ b1,
         const float* __restrict__ b2, const char* __restrict__ ws,
         float* __restrict__ out)
{
    __shared__ __align__(16) char acts[PTS_PER_BLK * ROWB];  // 67,584 B
    __shared__ __align__(16) char wbuf[65536];
    __shared__ __align__(16) char bbuf[2048];                // b0|b1|b2|b3p
    const int tid = threadIdx.x;
    const int lane = tid & 63;
    const int wv = tid >> 6;
    const int l15 = lane & 15;
    const int g = lane >> 4;
    const int mrow0 = wv * 32;

    // ---- stage0: W0P (8KB, linear — 64B rows don't conflict) + biases into bbuf ----
    {
        short8 v0 = *(const short8*)(ws + WS_W0P + tid * 16);
        short8 v1 = *(const short8*)(ws + WS_W0P + (256 + tid) * 16);
        *(short8*)(wbuf + tid * 16) = v0;
        *(short8*)(wbuf + (256 + tid) * 16) = v1;
        if (tid < 32)       ((float4*)bbuf)[tid] = ((const float4*)b0)[tid];
        else if (tid < 64)  ((float4*)bbuf)[tid] = ((const float4*)b1)[tid - 32];
        else if (tid < 96)  ((float4*)bbuf)[tid] = ((const float4*)b2)[tid - 64];
        else if (tid < 112) ((float4*)bbuf)[tid] = ((const float4*)(ws + WS_B3P))[tid - 96];
    }
    // ---- staging (lanes 0-31: one point per lane): xyz normalize, 9-slot hi/lo L0 input ----
    if (lane < 32) {
        const int n = blockIdx.x * PTS_PER_BLK + mrow0 + lane;
        const float x = xyz[3 * n + 0];
        const float y = xyz[3 * n + 1];
        const float z = xyz[3 * n + 2];
        const float xn = 2.0f * (x - amn[0]) * fast_rcp(amx[0] - amn[0]) - 1.0f;
        const float yn = 2.0f * (y - amn[1]) * fast_rcp(amx[1] - amn[1]) - 1.0f;
        const float zn = 2.0f * (z - amn[2]) * fast_rcp(amx[2] - amn[2]) - 1.0f;
        short xh, xl, yh, yl, zh, zl;
        split_bf(xn, xh, xl);
        split_bf(yn, yh, yl);
        split_bf(zn, zh, zl);
        short8 s0v; short8 zer = {0, 0, 0, 0, 0, 0, 0, 0};
        s0v[0] = xh; s0v[1] = yh; s0v[2] = zh; s0v[3] = xl;
        s0v[4] = yl; s0v[5] = zl; s0v[6] = xh; s0v[7] = yh;
        short8 s1v = zer; s1v[0] = zh;
        char* row = acts + (mrow0 + lane) * ROWB;
        *(short8*)(row) = s0v;
        *(short8*)(row + 16) = s1v;
        *(short8*)(row + 32) = zer;
        *(short8*)(row + 48) = zer;
    }
    __syncthreads();

    // ---- layer 0: K=32, A = W0P from LDS (linear 64B rows), 2 tiles ----
    {
        const float* bp = (const float*)bbuf;  // b0
        float4v acc[8][2];
#pragma unroll
        for (int ft = 0; ft < 8; ++ft) {
            float4v bv = *(const float4v*)(bp + ft * 16 + g * 4);
            bv *= LOG2E;
            acc[ft][0] = bv;
            acc[ft][1] = bv;
        }
        short8 B[2];
#pragma unroll
        for (int t = 0; t < 2; ++t)
            B[t] = *(const short8*)(acts + (mrow0 + t * 16 + l15) * ROWB + 16 * g);
        short8 A[8];
#pragma unroll
        for (int ft = 0; ft < 8; ++ft)
            A[ft] = *(const short8*)(wbuf + (ft * 16 + l15) * 64 + g * 16);
#pragma unroll
        for (int ft = 0; ft < 8; ++ft) {
            acc[ft][0] = mfma16(A[ft], B[0], acc[ft][0]);
            acc[ft][1] = mfma16(A[ft], B[1], acc[ft][1]);
        }
        CBAR();
#pragma unroll
        for (int ft = 0; ft < 8; ++ft) {
#pragma unroll
            for (int t = 0; t < 2; ++t) {
                char* rowp = acts + (mrow0 + t * 16 + l15) * ROWB;
                float s0 = sp_log2(acc[ft][t].x);
                float s1 = sp_log2(acc[ft][t].y);
                float s2 = sp_log2(acc[ft][t].z);
                float s3 = sp_log2(acc[ft][t].w);
                unsigned hx, lx, hy, ly;
                pack2_hl(s0, s1, hx, lx);
                pack2_hl(s2, s3, hy, ly);
                uint2v hw, lw;
                hw.x = hx; hw.y = hy;
                lw.x = lx; lw.y = ly;
                *(uint2v*)(rowp + (ft * 16 + g * 4) * 2) = hw;
                *(uint2v*)(rowp + 256 + (ft * 16 + g * 4) * 2) = lw;
            }
        }
        CBAR();
    }
    __syncthreads();   // all waves done reading W0P before W1 overwrites wbuf

    // ---- layer 1 ----
    stage_swz<8>(ws + WS_W1HI, wbuf, tid);
    stage_swz<8>(ws + WS_W1LO, wbuf + 32768, tid);
    __syncthreads();
    mfma_layer_lds<8, true>(acts, mrow0, l15, g, wbuf, wbuf + 32768,
                            (const float*)(bbuf + 512), LOG2E);
    __syncthreads();
    // ---- layer 2 ----
    stage_swz<8>(ws + WS_W2HI, wbuf, tid);
    stage_swz<8>(ws + WS_W2LO, wbuf + 32768, tid);
    __syncthreads();
    mfma_layer_lds<8, true>(acts, mrow0, l15, g, wbuf, wbuf + 32768,
                            (const float*)(bbuf + 1024), LOG2E);
    __syncthreads();
    // ---- layer 3 (+ TF staged alongside) ----
    stage_swz<4>(ws + WS_W3HI, wbuf + WB_W3HI, tid);
    stage_swz<4>(ws + WS_W3LO, wbuf + WB_W3LO, tid);
    if (tid < 128) {
        short8 th = *(const short8*)(ws + WS_TFHI + tid * 16);
        *(short8*)(wbuf + WB_TFHI + tid * 16) = th;
    } else {
        short8 tl = *(const short8*)(ws + WS_TFLO + (tid - 128) * 16);
        *(short8*)(wbuf + WB_TFLO + (tid - 128) * 16) = tl;
    }
    __syncthreads();
    mfma_layer_lds<4, false>(acts, mrow0, l15, g, wbuf + WB_W3HI, wbuf + WB_W3LO,
                             (const float*)(bbuf + 1536), 1.0f);

    // ---- tail part 1 (lanes 0-31): hierarchical softmax over own point's logits, pack p ----
    if (lane < 32) {
        char* rowp = acts + (mrow0 + lane) * ROWB;
        const float* lrow = (const float*)rowp;   // fp32 logits [0,256)
#define LG(i) lrow[(i)]
        float p[NB];
#define BR(par, ch)                                         \
    do {                                                    \
        float a_ = p[par];                                  \
        float s_ = sigf(LG(ch));                            \
        p[ch] = a_ * s_;                                    \
        p[par] = a_ * (1.0f - s_);                          \
    } while (0)
#define SUB3(par, gt, c0, c1, c2)                                            \
    do {                                                                     \
        float a_ = p[par];                                                   \
        float g_ = sigf(LG(gt));                                             \
        float l0_ = LG(c0), l1_ = LG(c1), l2_ = LG(c2);                      \
        float m_ = fmaxf(l0_, fmaxf(l1_, l2_));                              \
        float e0_ = __expf(l0_ - m_);                                        \
        float e1_ = __expf(l1_ - m_);                                        \
        float e2_ = __expf(l2_ - m_);                                        \
        float inv_ = a_ * g_ * fast_rcp(e0_ + e1_ + e2_);                    \
        p[c0] = e0_ * inv_;                                                  \
        p[c1] = e1_ * inv_;                                                  \
        p[c2] = e2_ * inv_;                                                  \
        p[par] = a_ * (1.0f - g_);                                           \
    } while (0)
#define SUB5(par, gt, c0, c1, c2, c3, c4)                                    \
    do {                                                                     \
        float a_ = p[par];                                                   \
        float g_ = sigf(LG(gt));                                             \
        float l0_ = LG(c0), l1_ = LG(c1), l2_ = LG(c2), l3_ = LG(c3), l4_ = LG(c4); \
        float m_ = fmaxf(fmaxf(fmaxf(l0_, l1_), fmaxf(l2_, l3_)), l4_);      \
        float e0_ = __expf(l0_ - m_);                                        \
        float e1_ = __expf(l1_ - m_);                                        \
        float e2_ = __expf(l2_ - m_);                                        \
        float e3_ = __expf(l3_ - m_);                                        \
        float e4_ = __expf(l4_ - m_);                                        \
        float inv_ = a_ * g_ * fast_rcp(e0_ + e1_ + e2_ + e3_ + e4_);        \
        p[c0] = e0_ * inv_;                                                  \
        p[c1] = e1_ * inv_;                                                  \
        p[c2] = e2_ * inv_;                                                  \
        p[c3] = e3_ * inv_;                                                  \
        p[c4] = e4_ * inv_;                                                  \
        p[par] = a_ * (1.0f - g_);                                           \
    } while (0)

        {
            float s0_ = sigf(LG(0));
            float l1_ = LG(1), l2_ = LG(2), l3_ = LG(3);
            float m_ = fmaxf(l1_, fmaxf(l2_, l3_));
            float e1_ = __expf(l1_ - m_);
            float e2_ = __expf(l2_ - m_);
            float e3_ = __expf(l3_ - m_);
            float inv_ = s0_ * fast_rcp(e1_ + e2_ + e3_);
            p[1] = e1_ * inv_;
            p[2] = e2_ * inv_;
            p[3] = e3_ * inv_;
            p[0] = 1.0f - s0_;
        }
        BR(1, 4); BR(2, 5); BR(3, 6);
        BR(4, 7); BR(5, 8); BR(6, 9);
        BR(7, 10); BR(8, 11);
        SUB3(9, 55, 12, 13, 14);
        BR(12, 15);
        BR(13, 16); BR(14, 17);
        BR(16, 18); BR(17, 19);
        BR(18, 20); BR(19, 21);
        SUB3(15, 56, 22, 23, 24);
        SUB5(20, 57, 25, 28, 31, 34, 37);
        SUB5(21, 58, 40, 43, 46, 49, 52);
        BR(25, 26); BR(28, 29); BR(31, 32); BR(34, 35); BR(37, 38);
        BR(26, 27); BR(29, 30); BR(32, 33); BR(35, 36); BR(38, 39);
        BR(40, 41); BR(43, 44); BR(46, 47); BR(49, 50); BR(52, 53);
        BR(41, 42); BR(44, 45); BR(47, 48); BR(50, 51); BR(53, 54);

        // pack p into own row: hi plane [0,128), lo plane [128,256) (logit reads above done)
#pragma unroll
        for (int jj = 0; jj < 64; jj += 4) {
            float v0 = (jj + 0 < NB) ? p[jj + 0] : 0.0f;
            float v1 = (jj + 1 < NB) ? p[jj + 1] : 0.0f;
            float v2 = (jj + 2 < NB) ? p[jj + 2] : 0.0f;
            float v3 = (jj + 3 < NB) ? p[jj + 3] : 0.0f;
            unsigned hx, lx, hy, ly;
            pack2_hl(v0, v1, hx, lx);
            pack2_hl(v2, v3, hy, ly);
            uint2v hw, lw;
            hw.x = hx; hw.y = hy;
            lw.x = lx; lw.y = ly;
            *(uint2v*)(rowp + 2 * jj) = hw;
            *(uint2v*)(rowp + 128 + 2 * jj) = lw;
        }
    }
    CBAR();

    // ---- T_fwd = p @ tfs via MFMA (all lanes, per tile); A = TF from LDS ----
    {
        const short* Ahi_p = (const short*)(wbuf + WB_TFHI);
        const short* Alo_p = (const short*)(wbuf + WB_TFLO);
        short8 Ah0 = *(const short8*)(Ahi_p + l15 * 64 + 0 + g * 8);
        short8 Al0 = *(const short8*)(Alo_p + l15 * 64 + 0 + g * 8);
        short8 Ah1 = *(const short8*)(Ahi_p + l15 * 64 + 32 + g * 8);
        short8 Al1 = *(const short8*)(Alo_p + l15 * 64 + 32 + g * 8);
#pragma unroll
        for (int t = 0; t < 2; ++t) {
            char* rowp = acts + (mrow0 + t * 16 + l15) * ROWB;
            float4v acc = (float4v){0.f, 0.f, 0.f, 0.f};
            {
                short8 Bhi = *(const short8*)(rowp + 0 + 16 * g);
                short8 Blo = *(const short8*)(rowp + 128 + 0 + 16 * g);
                acc = mfma16(Ah0, Bhi, acc);
                acc = mfma16(Ah0, Blo, acc);
                acc = mfma16(Al0, Bhi, acc);
            }
            {
                short8 Bhi = *(const short8*)(rowp + 64 + 16 * g);
                short8 Blo = *(const short8*)(rowp + 128 + 64 + 16 * g);
                acc = mfma16(Ah1, Bhi, acc);
                acc = mfma16(Ah1, Blo, acc);
                acc = mfma16(Al1, Bhi, acc);
            }
            CBAR();
            // write T to [256,320) — disjoint from p reads [0,256), no hazard
            *(float4v*)(rowp + 256 + g * 16) = acc;
        }
    }
    CBAR();

    // ---- tail part 2 (ALL 64 lanes, per tile): stream T rows coalesced to tf output ----
#pragma unroll
    for (int t = 0; t < 2; ++t) {
        const int pt = lane >> 2;
        const int j = lane & 3;
        const int n = blockIdx.x * PTS_PER_BLK + mrow0 + t * 16 + pt;
        float4v tv = *(const float4v*)(acts + (mrow0 + t * 16 + pt) * ROWB + 256 + 16 * j);
        float4* tf = (float4*)(out + 16 * (size_t)NPTS);
        tf[4 * n + j] = make_float4(tv.x, tv.y, tv.z, tv.w);
    }
}

// ======================= kernel 2: pose tail (elementwise, memory-bound) =======================
// Reads T_fwd back from out's tf section (stream-ordered after skin_mlp), plus xyz/quats;
// writes x_bar, rot_bar, quat_bar. ~40 VGPRs, no LDS -> full occupancy, HBM-bound ~82 MB.
__global__ void __launch_bounds__(256)
pose_kernel(const float* __restrict__ xyz, const float* __restrict__ quats,
            float* __restrict__ out)
{
    const int n = blockIdx.x * 256 + threadIdx.x;
    const float4* tf = (const float4*)(out + 16 * (size_t)NPTS);
    const float4 t0v = tf[4 * n + 0];
    const float4 t1v = tf[4 * n + 1];
    const float4 t2v = tf[4 * n + 2];

    const float x = xyz[3 * n + 0];
    const float y = xyz[3 * n + 1];
    const float z = xyz[3 * n + 2];

    const float xb0 = fmaf(t0v.x, x, fmaf(t0v.y, y, fmaf(t0v.z, z, t0v.w)));
    const float xb1 = fmaf(t1v.x, x, fmaf(t1v.y, y, fmaf(t1v.z, z, t1v.w)));
    const float xb2 = fmaf(t2v.x, x, fmaf(t2v.y, y, fmaf(t2v.z, z, t2v.w)));

    const float4 qv = ((const float4*)quats)[n];
    float qr = qv.x, qx = qv.y, qy = qv.z, qz = qv.w;
    {
        float inv = fast_rsq(qr * qr + qx * qx + qy * qy + qz * qz);
        qr *= inv; qx *= inv; qy *= inv; qz *= inv;
    }
    const float R00 = 1.0f - 2.0f * (qy * qy + qz * qz);
    const float R01 = 2.0f * (qx * qy - qr * qz);
    const float R02 = 2.0f * (qx * qz + qr * qy);
    const float R10 = 2.0f * (qx * qy + qr * qz);
    const float R11 = 1.0f - 2.0f * (qx * qx + qz * qz);
    const float R12 = 2.0f * (qy * qz - qr * qx);
    const float R20 = 2.0f * (qx * qz - qr * qy);
    const float R21 = 2.0f * (qy * qz + qr * qx);
    const float R22 = 1.0f - 2.0f * (qx * qx + qy * qy);

    const float B00 = t0v.x * R00 + t0v.y * R10 + t0v.z * R20;
    const float B01 = t0v.x * R01 + t0v.y * R11 + t0v.z * R21;
    const float B02 = t0v.x * R02 + t0v.y * R12 + t0v.z * R22;
    const float B10 = t1v.x * R00 + t1v.y * R10 + t1v.z * R20;
    const float B11 = t1v.x * R01 + t1v.y * R11 + t1v.z * R21;
    const float B12 = t1v.x * R02 + t1v.y * R12 + t1v.z * R22;
    const float B20 = t2v.x * R00 + t2v.y * R10 + t2v.z * R20;
    const float B21 = t2v.x * R01 + t2v.y * R11 + t2v.z * R21;
    const float B22 = t2v.x * R02 + t2v.y * R12 + t2v.z * R22;

    const float t0 = 1.0f + B00 + B11 + B22;
    const float t1 = 1.0f + B00 - B11 - B22;
    const float t2 = 1.0f - B00 + B11 - B22;
    const float t3 = 1.0f - B00 - B11 + B22;
    const float s0 = 0.5f * fast_rsq(fmaxf(t0, 1e-8f));
    const float s1 = 0.5f * fast_rsq(fmaxf(t1, 1e-8f));
    const float s2 = 0.5f * fast_rsq(fmaxf(t2, 1e-8f));
    const float s3 = 0.5f * fast_rsq(fmaxf(t3, 1e-8f));
    const float q0w = t0 * s0, q0x = (B21 - B12) * s0, q0y = (B02 - B20) * s0, q0z = (B10 - B01) * s0;
    const float q1w = (B21 - B12) * s1, q1x = t1 * s1, q1y = (B01 + B10) * s1, q1z = (B02 + B20) * s1;
    const float q2w = (B02 - B20) * s2, q2x = (B01 + B10) * s2, q2y = t2 * s2, q2z = (B12 + B21) * s2;
    const float q3w = (B10 - B01) * s3, q3x = (B02 + B20) * s3, q3y = (B12 + B21) * s3, q3z = t3 * s3;

    int best = 0;
    float tb = t0;
    if (t1 > tb) { best = 1; tb = t1; }
    if (t2 > tb) { best = 2; tb = t2; }
    if (t3 > tb) { best = 3; tb = t3; }

    float Qw = (best == 0) ? q0w : (best == 1) ? q1w : (best == 2) ? q2w : q3w;
    float Qx = (best == 0) ? q0x : (best == 1) ? q1x : (best == 2) ? q2x : q3x;
    float Qy = (best == 0) ? q0y : (best == 1) ? q1y : (best == 2) ? q2y : q3y;
    float Qz = (best == 0) ? q0z : (best == 1) ? q1z : (best == 2) ? q2z : q3z;
    {
        float inv = fast_rsq(Qw * Qw + Qx * Qx + Qy * Qy + Qz * Qz);
        Qw *= inv; Qx *= inv; Qy *= inv; Qz *= inv;
    }

    out[3 * n + 0] = xb0;
    out[3 * n + 1] = xb1;
    out[3 * n + 2] = xb2;
    float* rb = out + 3 * (size_t)NPTS;
    rb[9 * n + 0] = B00; rb[9 * n + 1] = B01; rb[9 * n + 2] = B02;
    rb[9 * n + 3] = B10; rb[9 * n + 4] = B11; rb[9 * n + 5] = B12;
    rb[9 * n + 6] = B20; rb[9 * n + 7] = B21; rb[9 * n + 8] = B22;
    float4* qb = (float4*)(out + 12 * (size_t)NPTS);
    qb[n] = make_float4(Qw, Qx, Qy, Qz);
}

extern "C" void kernel_launch(void* const* d_in, const int* in_sizes, int n_in,
                              void* d_out, int out_size, void* d_ws, size_t ws_size,
                              hipStream_t stream) {
    const float* xyz = (const float*)d_in[0];
    const float* quats = (const float*)d_in[1];
    const float* tfs = (const float*)d_in[2];
    const float* amn = (const float*)d_in[3];
    const float* amx = (const float*)d_in[4];
    const float* W0 = (const float*)d_in[5];
    const float* b0 = (const float*)d_in[6];
    const float* W1 = (const float*)d_in[7];
    const float* b1 = (const float*)d_in[8];
    const float* W2 = (const float*)d_in[9];
    const float* b2 = (const float*)d_in[10];
    const float* W3 = (const float*)d_in[11];
    const float* b3 = (const float*)d_in[12];
    float* out = (float*)d_out;
    char* ws = (char*)d_ws;

    hipLaunchKernelGGL(prep_kernel, dim3(64), dim3(256), 0, stream, W0, W1, W2, W3, b3, tfs, ws);
    hipLaunchKernelGGL(skin_mlp, dim3(NPTS / PTS_PER_BLK), dim3(BLK), 0, stream,
                       xyz, amn, amx, b0, b1, b2, (const char*)ws, out);
    hipLaunchKernelGGL(pose_kernel, dim3(NPTS / 256), dim3(256), 0, stream,
                       xyz, quats, out);
}